// Round 4
// baseline (243.160 us; speedup 1.0000x reference)
//
#include <hip/hip_runtime.h>
#include <hip/hip_cooperative_groups.h>
#include <math.h>

namespace cg = cooperative_groups;

// Problem: S=4096, B=16, H=1024
//   energies[b,s] = hidden[b,:] . (W @ enc[s,b,:] + b_attn)
//   out[b,0,s]    = softmax_s(energies[b,s])
// Reassociated: energies[b,s] = v[b,:] . enc[s,b,:] (+ const_b, cancels in
// softmax shift-invariance), v = hidden @ W.  b_attn never read.
//
// Primary path: ONE cooperative kernel (512 blocks = 2/CU, verified via
// occupancy query + checked launch return). Fallback: 3 plain kernels.

#define SS 4096
#define BB 16
#define HH 1024
#define NBLK 512
#define NTHR 256
#define NWAVE (NBLK * NTHR / 64)   // 2048
#define PW (SS * BB / NWAVE)       // 32 pairs per wave
#define KC 8                       // split-k chunks (coop GEMV)

typedef float f4 __attribute__((ext_vector_type(4)));

__device__ __forceinline__ unsigned flipf(float f) {
    unsigned u = __float_as_uint(f);
    return (u & 0x80000000u) ? ~u : (u | 0x80000000u);
}
__device__ __forceinline__ float unflipf(unsigned u) {
    return __uint_as_float((u & 0x80000000u) ? (u & 0x7fffffffu) : ~u);
}

// ---------------- shared device helpers ------------------------------------
__device__ __forceinline__ void gemv_splitk_body(int tid,
                                                 const float* __restrict__ hidden,
                                                 const float* __restrict__ W,
                                                 float* __restrict__ v) {
    // tid in [0, 131072): kc = tid>>14 (8 chunks of 128 k), i = tid&16383.
    int kc = tid >> 14;
    int i  = tid & 16383;
    int b  = i >> 10;
    int h  = i & (HH - 1);
    const float* hrow = hidden + b * HH + kc * (HH / KC);
    const float* Wp   = W + (size_t)(kc * (HH / KC)) * HH + h;
    float a0 = 0.f, a1 = 0.f, a2 = 0.f, a3 = 0.f;
    #pragma unroll 4
    for (int k = 0; k < HH / KC; k += 4) {
        a0 += hrow[k + 0] * Wp[(k + 0) * HH];
        a1 += hrow[k + 1] * Wp[(k + 1) * HH];
        a2 += hrow[k + 2] * Wp[(k + 2) * HH];
        a3 += hrow[k + 3] * Wp[(k + 3) * HH];
    }
    atomicAdd(&v[i], (a0 + a1) + (a2 + a3));
}

// ---------------- PRIMARY: single cooperative kernel -----------------------
__global__ void __launch_bounds__(NTHR, 2)
fused_attn_kernel(const float* __restrict__ hidden,
                  const float* __restrict__ enc,
                  const float* __restrict__ W,
                  float* __restrict__ out,
                  float* __restrict__ v,
                  unsigned* __restrict__ maxbits,
                  float* __restrict__ sums) {
    cg::grid_group grid = cg::this_grid();

    // P1: split-k GEMV -> v (ws pre-zeroed by memsetAsync)
    gemv_splitk_body(blockIdx.x * NTHR + threadIdx.x, hidden, W, v);
    grid.sync();

    // P2: PW energies per wave, butterfly-replicated into registers
    int ww   = (blockIdx.x * NTHR + threadIdx.x) >> 6;  // wave 0..2047
    int lane = threadIdx.x & 63;
    int b  = ww & (BB - 1);
    int sg = ww >> 4;                  // 0..127, s = sg*PW + j
    const f4* v4 = (const f4*)(v + b * HH);
    f4 vv[4];
    #pragma unroll
    for (int i = 0; i < 4; ++i) vv[i] = v4[i * 64 + lane];

    float e[PW];
    #pragma unroll
    for (int j = 0; j < PW; ++j) {
        const f4* e4 = (const f4*)(enc + (size_t)((sg * PW + j) * BB + b) * HH);
        f4 a0 = e4[0 * 64 + lane];
        f4 a1 = e4[1 * 64 + lane];
        f4 a2 = e4[2 * 64 + lane];
        f4 a3 = e4[3 * 64 + lane];
        f4 p  = a0 * vv[0] + a1 * vv[1] + a2 * vv[2] + a3 * vv[3];
        e[j]  = (p.x + p.y) + (p.z + p.w);
    }
    #pragma unroll
    for (int j = 0; j < PW; ++j) {
        #pragma unroll
        for (int off = 32; off; off >>= 1) e[j] += __shfl_xor(e[j], off, 64);
    }

    // P3: per-b global max via 16-slot flipped-float atomicMax
    float m = e[0];
    #pragma unroll
    for (int j = 1; j < PW; ++j) m = fmaxf(m, e[j]);
    if (lane == 0) atomicMax(&maxbits[b], flipf(m));
    grid.sync();

    // P4: exp + per-b sum
    float mb = unflipf(maxbits[b]);
    float lsum = 0.f;
    #pragma unroll
    for (int j = 0; j < PW; ++j) {
        e[j] = expf(e[j] - mb);
        lsum += e[j];
    }
    if (lane == 0) atomicAdd(&sums[b], lsum);
    grid.sync();

    // P5: normalize; lanes 0..PW/4-1 each store one float4 (coalesced)
    float inv = 1.0f / sums[b];
    if (lane < PW / 4) {
        f4 w;
        w.x = e[4 * lane + 0] * inv;
        w.y = e[4 * lane + 1] * inv;
        w.z = e[4 * lane + 2] * inv;
        w.w = e[4 * lane + 3] * inv;
        *(f4*)(out + b * SS + sg * PW + 4 * lane) = w;
    }
}

// ---------------- FALLBACK: 3 plain kernels --------------------------------
__global__ void __launch_bounds__(NTHR)
gemv_atomic_kernel(const float* __restrict__ hidden,
                   const float* __restrict__ W,
                   float* __restrict__ v) {
    gemv_splitk_body(blockIdx.x * NTHR + threadIdx.x, hidden, W, v);
}

#define PP 8
__global__ void __launch_bounds__(NTHR)
energies_kernel(const float* __restrict__ enc,
                const float* __restrict__ v,
                float* __restrict__ out) {
    int w    = (blockIdx.x * blockDim.x + threadIdx.x) >> 6;  // 0..8191
    int lane = threadIdx.x & 63;
    int b  = w & (BB - 1);
    int sg = w >> 4;               // 0..511
    const f4* v4 = (const f4*)(v + b * HH);
    f4 vv[4];
    #pragma unroll
    for (int i = 0; i < 4; ++i) vv[i] = v4[i * 64 + lane];
    float acc[PP];
    #pragma unroll
    for (int j = 0; j < PP; ++j) {
        const f4* e4 = (const f4*)(enc + (size_t)((sg * PP + j) * BB + b) * HH);
        f4 a0 = e4[0 * 64 + lane];
        f4 a1 = e4[1 * 64 + lane];
        f4 a2 = e4[2 * 64 + lane];
        f4 a3 = e4[3 * 64 + lane];
        f4 p  = a0 * vv[0] + a1 * vv[1] + a2 * vv[2] + a3 * vv[3];
        acc[j] = (p.x + p.y) + (p.z + p.w);
    }
    #pragma unroll
    for (int j = 0; j < PP; ++j) {
        float a = acc[j];
        #pragma unroll
        for (int off = 32; off; off >>= 1) a += __shfl_xor(a, off, 64);
        if (lane == 0) out[b * SS + sg * PP + j] = a;
    }
}

__global__ void __launch_bounds__(NTHR)
softmax_kernel(float* __restrict__ out) {
    int b = blockIdx.x;
    float* row = out + b * SS;
    int t = threadIdx.x;
    float vals[16];
    float m = -INFINITY;
    #pragma unroll
    for (int i = 0; i < 16; ++i) {
        vals[i] = row[t + i * 256];
        m = fmaxf(m, vals[i]);
    }
    #pragma unroll
    for (int off = 32; off; off >>= 1) m = fmaxf(m, __shfl_xor(m, off, 64));
    __shared__ float redm[4];
    __shared__ float reds[4];
    int wid = t >> 6;
    if ((t & 63) == 0) redm[wid] = m;
    __syncthreads();
    m = fmaxf(fmaxf(redm[0], redm[1]), fmaxf(redm[2], redm[3]));
    float sum = 0.f;
    #pragma unroll
    for (int i = 0; i < 16; ++i) {
        vals[i] = expf(vals[i] - m);
        sum += vals[i];
    }
    #pragma unroll
    for (int off = 32; off; off >>= 1) sum += __shfl_xor(sum, off, 64);
    if ((t & 63) == 0) reds[wid] = sum;
    __syncthreads();
    sum = reds[0] + reds[1] + reds[2] + reds[3];
    float inv = 1.0f / sum;
    #pragma unroll
    for (int i = 0; i < 16; ++i) row[t + i * 256] = vals[i] * inv;
}

extern "C" void kernel_launch(void* const* d_in, const int* in_sizes, int n_in,
                              void* d_out, int out_size, void* d_ws, size_t ws_size,
                              hipStream_t stream) {
    const float* hidden = (const float*)d_in[0];   // [1,B,H]
    const float* enc    = (const float*)d_in[1];   // [S,B,H]
    const float* W      = (const float*)d_in[2];   // [H,H]
    // d_in[3] = b_attn: cancels in softmax (zero in setup anyway)
    float* out = (float*)d_out;                    // [B,1,S]

    float*    v       = (float*)d_ws;              // 16384 floats
    unsigned* maxbits = (unsigned*)(v + BB * HH);  // 16
    float*    sums    = (float*)(maxbits + BB);    // 16

    // zero v / maxbits / sums every call (atomics accumulate into them)
    hipMemsetAsync(d_ws, 0, (BB * HH + 2 * BB) * sizeof(float), stream);

    // host-side capability check (pure queries: capture-safe, deterministic)
    int dev = 0;
    hipGetDevice(&dev);
    int numCU = 0;
    hipDeviceGetAttribute(&numCU, hipDeviceAttributeMultiprocessorCount, dev);
    int maxBlk = 0;
    hipError_t qe = hipOccupancyMaxActiveBlocksPerMultiprocessor(
        &maxBlk, (const void*)fused_attn_kernel, NTHR, 0);

    hipError_t le = hipErrorUnknown;
    if (qe == hipSuccess && (long)maxBlk * numCU >= NBLK) {
        void* args[] = {(void*)&hidden, (void*)&enc, (void*)&W,
                        (void*)&out, (void*)&v, (void*)&maxbits, (void*)&sums};
        le = hipLaunchCooperativeKernel((void*)fused_attn_kernel,
                                        dim3(NBLK), dim3(NTHR), args, 0, stream);
    }
    if (le != hipSuccess) {
        // fallback: 3 plain launches (v already being zeroed above)
        hipLaunchKernelGGL(gemv_atomic_kernel, dim3(NBLK), dim3(NTHR), 0, stream,
                           hidden, W, v);
        hipLaunchKernelGGL(energies_kernel, dim3(SS * BB / PP / 4), dim3(NTHR),
                           0, stream, enc, v, out);
        hipLaunchKernelGGL(softmax_kernel, dim3(BB), dim3(NTHR), 0, stream, out);
    }
}

// Round 5
// 57.222 us; speedup vs baseline: 4.2494x; 4.2494x over previous
//
#include <hip/hip_runtime.h>
#include <math.h>

// Problem: S=4096, B=16, H=1024
//   energies[b,s] = hidden[b,:] . (W @ enc[s,b,:] + b_attn)
//   out[b,0,s]    = softmax_s(energies[b,s])
// Reassociated: energies[b,s] = v[b,:] . enc[s,b,:] (+ const_b, which cancels
// under softmax shift-invariance), v = hidden @ W.  b_attn never read.
//
// 4 plain launches (cooperative fusion refuted in R4: regs spilled to scratch,
// 243 us). Nontemporal loads refuted in R2 (lose L3 reuse).
//   A1: split-k partial GEMV (1024 blocks, 64-deep)   ~3 us
//   A2: reduce 16 partials -> v (64 blocks)           ~1 us
//   B : energies, v in 16 VGPRs, 4 pairs/wave         ~45 us (BW-bound)
//   C : per-b softmax in-place on d_out (16 blocks)   ~3 us

#define SS 4096
#define BB 16
#define HH 1024
#define KC 16          // k-chunks for split-k GEMV
#define KLEN (HH / KC) // 64
#define PP 4           // enc rows (pairs) per wave in kernel B

typedef float f4 __attribute__((ext_vector_type(4)));

// ---- A1: partial[kc][b*HH+h] = sum_{k in chunk kc} hidden[b,k] * W[k,h] ----
// 1024 blocks x 256 threads. Block -> (kc, b, h-chunk of 256): W reads are
// coalesced over h (1 KB/inst); hidden[b,k] is block-uniform (scalar loads).
__global__ void __launch_bounds__(256)
gemv_partial_kernel(const float* __restrict__ hidden,
                    const float* __restrict__ W,
                    float* __restrict__ partial) {
    int blk = blockIdx.x;          // 0..1023
    int kc  = blk >> 6;            // 16 chunks
    int rb  = blk & 63;            // b(16) x hchunk(4)
    int b   = rb >> 2;
    int h   = ((rb & 3) << 8) | threadIdx.x;
    const float* hrow = hidden + b * HH + kc * KLEN;
    const float* Wp   = W + (size_t)(kc * KLEN) * HH + h;
    float a0 = 0.f, a1 = 0.f, a2 = 0.f, a3 = 0.f;
    #pragma unroll 4
    for (int k = 0; k < KLEN; k += 4) {
        a0 += hrow[k + 0] * Wp[(k + 0) * HH];
        a1 += hrow[k + 1] * Wp[(k + 1) * HH];
        a2 += hrow[k + 2] * Wp[(k + 2) * HH];
        a3 += hrow[k + 3] * Wp[(k + 3) * HH];
    }
    partial[kc * (BB * HH) + b * HH + h] = (a0 + a1) + (a2 + a3);
}

// ---- A2: v[i] = sum_kc partial[kc][i] ------------------------------------
__global__ void __launch_bounds__(256)
gemv_reduce_kernel(const float* __restrict__ partial,
                   float* __restrict__ v) {
    int i = blockIdx.x * 256 + threadIdx.x;   // 0..16383
    float s = 0.f;
    #pragma unroll
    for (int kc = 0; kc < KC; ++kc) s += partial[kc * (BB * HH) + i];
    v[i] = s;
}

// ---- B: energies[b,s] = v[b,:] . enc[s,b,:] ------------------------------
// One wave per 4 pairs sharing b. v row (4 KB) lives in 16 VGPRs (loaded
// once per wave); each pair is 4x float4 loads (64 lanes x 16 B = 1 KB
// coalesced, 16 loads in flight across the 4 pairs), then 6-step shfl_xor
// reduces and ONE float4 store from lane 0. Plain loads keep enc in L3 for
// the timed replays.
__global__ void __launch_bounds__(256, 4)
energies_kernel(const float* __restrict__ enc,
                const float* __restrict__ v,
                float* __restrict__ out) {
    int w    = (blockIdx.x * blockDim.x + threadIdx.x) >> 6;  // wave 0..16383
    int lane = threadIdx.x & 63;
    int b  = w & (BB - 1);
    int sg = w >> 4;               // 0..1023, covers s in [sg*PP, sg*PP+PP)
    const f4* v4 = (const f4*)(v + b * HH);
    f4 vv[4];
    #pragma unroll
    for (int i = 0; i < 4; ++i) vv[i] = v4[i * 64 + lane];
    float acc[PP];
    #pragma unroll
    for (int j = 0; j < PP; ++j) {
        const f4* e4 = (const f4*)(enc + (size_t)((sg * PP + j) * BB + b) * HH);
        f4 a0 = e4[0 * 64 + lane];
        f4 a1 = e4[1 * 64 + lane];
        f4 a2 = e4[2 * 64 + lane];
        f4 a3 = e4[3 * 64 + lane];
        f4 p  = a0 * vv[0] + a1 * vv[1] + a2 * vv[2] + a3 * vv[3];
        acc[j] = (p.x + p.y) + (p.z + p.w);
    }
    #pragma unroll
    for (int j = 0; j < PP; ++j) {
        #pragma unroll
        for (int off = 32; off; off >>= 1) acc[j] += __shfl_xor(acc[j], off, 64);
    }
    if (lane == 0) {
        f4 o;
        o.x = acc[0]; o.y = acc[1]; o.z = acc[2]; o.w = acc[3];
        *(f4*)(out + b * SS + sg * PP) = o;
    }
}

// ---- C: in-place softmax over s, one 256-thread block per b --------------
__global__ void __launch_bounds__(256)
softmax_kernel(float* __restrict__ out) {
    int b = blockIdx.x;
    float* row = out + b * SS;
    int t = threadIdx.x;                 // 16 values per thread
    float vals[16];
    float m = -INFINITY;
    #pragma unroll
    for (int i = 0; i < 16; ++i) {
        vals[i] = row[t + i * 256];
        m = fmaxf(m, vals[i]);
    }
    #pragma unroll
    for (int off = 32; off; off >>= 1) m = fmaxf(m, __shfl_xor(m, off, 64));
    __shared__ float redm[4];
    __shared__ float reds[4];
    int wid = t >> 6;
    if ((t & 63) == 0) redm[wid] = m;
    __syncthreads();
    m = fmaxf(fmaxf(redm[0], redm[1]), fmaxf(redm[2], redm[3]));

    float sum = 0.f;
    #pragma unroll
    for (int i = 0; i < 16; ++i) {
        vals[i] = expf(vals[i] - m);
        sum += vals[i];
    }
    #pragma unroll
    for (int off = 32; off; off >>= 1) sum += __shfl_xor(sum, off, 64);
    if ((t & 63) == 0) reds[wid] = sum;
    __syncthreads();
    sum = reds[0] + reds[1] + reds[2] + reds[3];
    float inv = 1.0f / sum;
    #pragma unroll
    for (int i = 0; i < 16; ++i) row[t + i * 256] = vals[i] * inv;
}

extern "C" void kernel_launch(void* const* d_in, const int* in_sizes, int n_in,
                              void* d_out, int out_size, void* d_ws, size_t ws_size,
                              hipStream_t stream) {
    const float* hidden = (const float*)d_in[0];   // [1,B,H]
    const float* enc    = (const float*)d_in[1];   // [S,B,H]
    const float* W      = (const float*)d_in[2];   // [H,H]
    // d_in[3] = b_attn: cancels in softmax (and is zero in setup_inputs)
    float* out     = (float*)d_out;                // [B,1,S]
    float* v       = (float*)d_ws;                 // B*H floats    = 64 KB
    float* partial = v + BB * HH;                  // KC*B*H floats = 1 MB

    hipLaunchKernelGGL(gemv_partial_kernel, dim3(KC * 64), dim3(256), 0, stream,
                       hidden, W, partial);
    hipLaunchKernelGGL(gemv_reduce_kernel, dim3(BB * HH / 256), dim3(256), 0, stream,
                       partial, v);
    hipLaunchKernelGGL(energies_kernel, dim3(SS * BB / PP / 4), dim3(256), 0, stream,
                       enc, v, out);
    hipLaunchKernelGGL(softmax_kernel, dim3(BB), dim3(256), 0, stream, out);
}